// Round 8
// baseline (1513.383 us; speedup 1.0000x reference)
//
#include <hip/hip_runtime.h>
#include <math.h>

#define N_NODES_ 50000
#define N_EDGES_ 1000000
#define HID 128
#define NG 50
#define NF 128
#define NCOL 4
#define CSEG 258048            // 64-aligned per-color capacity (>> 250K + 18 sigma)
#define NKEY (NCOL * N_NODES_) // 200000
#define CHUNK 625              // 50000 = 80 * 625
#define NCHUNK_PER_C 80
#define NCHUNK (NCOL * NCHUNK_PER_C)
#define BLKS_PER_C 512         // persistent blocks per color in passA

typedef short s16x8 __attribute__((ext_vector_type(8)));
typedef float f32x4 __attribute__((ext_vector_type(4)));

__device__ __forceinline__ float sspf(float v) {
    // log(1+e^v) - log2, fast-math; for large v avoid inf
    float r = __logf(1.f + __expf(v)) - 0.69314718055994531f;
    return (v > 15.f) ? (v - 0.69314718055994531f) : r;
}

__device__ __forceinline__ unsigned int f2b(float f) {  // f32 -> bf16 (RNE), in low 16
    unsigned int u = __float_as_uint(f);
    return (u + 0x7fffu + ((u >> 16) & 1u)) >> 16;
}

// DPP row_shl:N within 16-lane rows: out[i] = in[i+N], 0 when i+N crosses the row.
template <int CTRL>
__device__ __forceinline__ float dpp_shl_f(float v) {
    return __int_as_float(__builtin_amdgcn_update_dpp(
        0, __float_as_int(v), CTRL, 0xF, 0xF, false));
}

// ---------------- histogram over (color,dst) keys ----------------
__global__ __launch_bounds__(256) void hist_kernel(const int* __restrict__ colors,
                                                   const int* __restrict__ edge_index,
                                                   int* __restrict__ hist) {
    int e = blockIdx.x * 256 + threadIdx.x;
    if (e < N_EDGES_) {
        int key = colors[e] * N_NODES_ + edge_index[N_EDGES_ + e];
        atomicAdd(&hist[key], 1);
    }
}

// ---------------- per-chunk exclusive scan (in place) ----------------
__global__ __launch_bounds__(256) void scan1_kernel(int* __restrict__ hist,
                                                    int* __restrict__ csum) {
    __shared__ int s[CHUNK];
    int b = blockIdx.x;                  // 0..319
    int c = b / NCHUNK_PER_C, ch = b % NCHUNK_PER_C;
    int gofs = c * N_NODES_ + ch * CHUNK;
    for (int i = threadIdx.x; i < CHUNK; i += 256) s[i] = hist[gofs + i];
    __syncthreads();
    if (threadIdx.x == 0) {
        int run = 0;
        for (int i = 0; i < CHUNK; ++i) { int t = s[i]; s[i] = run; run += t; }
        csum[b] = run;
    }
    __syncthreads();
    for (int i = threadIdx.x; i < CHUNK; i += 256) hist[gofs + i] = s[i];
}

__global__ __launch_bounds__(64) void scan2_kernel(const int* __restrict__ csum,
                                                   int* __restrict__ cbase,
                                                   int* __restrict__ g_cnt) {
    int c = threadIdx.x;
    if (c < NCOL) {
        int run = 0;
        for (int j = 0; j < NCHUNK_PER_C; ++j) {
            cbase[c * NCHUNK_PER_C + j] = run;
            run += csum[c * NCHUNK_PER_C + j];
        }
        g_cnt[c] = run;
    }
}

__global__ __launch_bounds__(256) void scan3_kernel(int* __restrict__ hist,
                                                    const int* __restrict__ cbase) {
    int b = blockIdx.x;
    int c = b / NCHUNK_PER_C, ch = b % NCHUNK_PER_C;
    int gofs = c * N_NODES_ + ch * CHUNK;
    int add = cbase[b];
    for (int i = threadIdx.x; i < CHUNK; i += 256) hist[gofs + i] += add;
}

// ---------------- fill pad records + zero hist + zero agg (fused) ----------------
// record = 3 ints: {eid, (d<<16)|src, cw_bits}. Pad: eid=-1, d=0xFFFF (matches only
// other pads; 65535 > any real d<50000), src=0, cw=0 (exact zero so the fma-masked
// DPP scan can never touch Inf/NaN from pad lanes).
__global__ __launch_bounds__(256) void fill_kernel(int* __restrict__ erec,
                                                   int* __restrict__ base,
                                                   float4* __restrict__ agg4) {
    int i = blockIdx.x * 256 + threadIdx.x;
    int nthr = gridDim.x * 256;
    if (i < NCOL * CSEG) {
        erec[3 * i + 0] = -1;
        erec[3 * i + 1] = (int)0xFFFF0000u;
        erec[3 * i + 2] = 0;
    }
    if (i < NKEY) base[i] = 0;
    for (int j = i; j < N_NODES_ * HID / 4; j += nthr)
        agg4[j] = make_float4(0.f, 0.f, 0.f, 0.f);
}

// ---------------- scatter into (color,dst)-sorted order ----------------
// AoS 12B records: one dirty cache line per edge instead of 3 scattered stores.
__global__ __launch_bounds__(256) void scatter_kernel(const int* __restrict__ colors,
                                                      const int* __restrict__ edge_index,
                                                      const float* __restrict__ edge_weight,
                                                      int* __restrict__ base,  // scanned hist (cursor)
                                                      int* __restrict__ erec) {
    int e = blockIdx.x * 256 + threadIdx.x;
    if (e < N_EDGES_) {
        int c = colors[e];
        int d = edge_index[N_EDGES_ + e];
        int s = edge_index[e];
        int key = c * N_NODES_ + d;
        int r = atomicAdd(&base[key], 1);
        float cwv = 0.5f * (__cosf(edge_weight[e] * 0.31415926535897932f) + 1.f);
        size_t slot = (size_t)(c * CSEG + r) * 3;
        erec[slot + 0] = e;
        erec[slot + 1] = (int)(((unsigned)d << 16) | (unsigned)s);
        erec[slot + 2] = (int)__float_as_uint(cwv);
    }
}

// ---------------- convert MLP weights to bf16 ----------------
// m1: zero-padded K (50->64). m2: k-columns permuted by tau so that phase-2's
// B-fragment is a pure register renaming of phase-1's packed MFMA output.
__global__ __launch_bounds__(256) void wconv_kernel(const float* __restrict__ m1w,
                                                    const float* __restrict__ m2w,
                                                    unsigned short* __restrict__ m1b16,
                                                    unsigned short* __restrict__ m2b16) {
    int idx = blockIdx.x * 256 + threadIdx.x;
    if (idx < NCOL * NF * 64) {
        int c = idx / (NF * 64);
        int rem = idx % (NF * 64);
        int n = rem / 64, k = rem % 64;
        float v = (k < NG) ? m1w[(c * NF + n) * NG + k] : 0.f;
        m1b16[idx] = (unsigned short)f2b(v);
    } else if (idx < NCOL * NF * 64 + NCOL * NF * NF) {
        int j = idx - NCOL * NF * 64;
        int cn = j / NF;            // c*NF + n
        int k = j % NF;
        int ks = k >> 5, qk = (k >> 3) & 3, jj = k & 7;
        int tau = ((2 * ks + (jj >> 2)) << 4) | (qk << 2) | (jj & 3);
        m2b16[j] = (unsigned short)f2b(m2w[cn * NF + tau]);
    }
}

// ---------------- fused edge pass ----------------
// Round-8: multi-tile persistent blocks. r5/r6 staged 32KB m2 per 64-edge tile
// (16384 x 32KB = 512MB L2 reads, 512B staged per edge of work) + 16384 block
// launches. Now 512 blocks/color stage m2 ONCE, barrier once, then grid-stride
// ~7.6 tiles each with no further barriers (sm2 read-only; waves independent).
// Per-tile atomic tail overlaps next tile's loads in the same wave. Atomic op
// count unchanged -> this round cleanly tests the atomic-wall hypothesis.
__global__ __launch_bounds__(256, 5) void passA_kernel(
    const float* __restrict__ edge_attr,
    const unsigned short* __restrict__ m1b16, const unsigned short* __restrict__ m2b16,
    const float* __restrict__ m1bias, const float* __restrict__ m2bias,
    const float* __restrict__ h, const int* __restrict__ erec,
    const int* __restrict__ g_cnt, float* __restrict__ agg) {

    __shared__ __align__(16) char sm2[32768];   // m2 (one color), XOR-swizzled rows

    int c = blockIdx.x >> 9;             // BLKS_PER_C blocks per color
    int bslot = blockIdx.x & (BLKS_PER_C - 1);
    int cnt = g_cnt[c];
    int ntiles = (cnt + 63) >> 6;

    int tid = threadIdx.x;
    int wv = tid >> 6;
    int l15 = tid & 15;
    int q = (tid >> 4) & 3;
    int e = (wv << 4) | l15;             // this thread's edge row in tile (MFMA col = l15)

    // ---- stage m2 into LDS once, swizzled: byte row*256 + (k0*16 ^ (row&7)<<4)
    {
        const uint4* g4 = (const uint4*)(m2b16 + (size_t)c * NF * NF);
#pragma unroll
        for (int i = 0; i < 8; ++i) {
            int c0 = tid + 256 * i;      // 0..2047 dwordx4 chunks
            int row = c0 >> 4;
            int k0 = c0 & 15;
            int dstb = row * 256 + ((k0 * 16) ^ ((row & 7) << 4));
            *(uint4*)(sm2 + dstb) = g4[c0];
        }
    }
    __syncthreads();                     // uniform; only barrier in the kernel

    const unsigned short* m1p = m1b16 + (size_t)c * NF * 64;
    const float* b1p = m1bias + c * NF;
    const float* b2p = m2bias + c * NF;
    int rowb0 = l15 * 256;               // LDS row base (row = m*16+l15)
    int sw = (l15 & 7) << 4;             // row XOR swizzle

    for (int tile = bslot; tile < ntiles; tile += BLKS_PER_C) {
        int pos0 = c * CSEG + tile * 64;

        // per-lane edge record (12B, coalesced; 4x replicated across q groups)
        size_t ri = (size_t)(pos0 + e) * 3;
        int eid = erec[ri + 0];
        unsigned w1 = (unsigned)erec[ri + 1];
        float cw = __int_as_float(erec[ri + 2]);   // exact 0 for pads
        int d = (int)(w1 >> 16);                   // pads: 65535 (only matches pads)
        int sidx = (int)(w1 & 0xFFFFu);

        // phase-1 B-fragments straight from global: lane (q,l15) reads edge_attr
        // row eid, floats [q*8+32ks, ...+8), zero-padded k>=50. 200B rows -> float2.
        union { s16x8 v; unsigned int u[4]; } bf0, bf1;
        {
            const float* ear = edge_attr + (size_t)((eid >= 0) ? eid : 0) * NG;
            float2 a0 = *(const float2*)(ear + q * 8 + 0);
            float2 a1 = *(const float2*)(ear + q * 8 + 2);
            float2 a2v = *(const float2*)(ear + q * 8 + 4);
            float2 a3 = *(const float2*)(ear + q * 8 + 6);
            bf0.u[0] = f2b(a0.x) | (f2b(a0.y) << 16);
            bf0.u[1] = f2b(a1.x) | (f2b(a1.y) << 16);
            bf0.u[2] = f2b(a2v.x) | (f2b(a2v.y) << 16);
            bf0.u[3] = f2b(a3.x) | (f2b(a3.y) << 16);
            float2 c0 = make_float2(0.f, 0.f), c1 = c0, c2 = c0, c3 = c0;
            int k1 = 32 + q * 8;
            if (q < 2) {
                c0 = *(const float2*)(ear + k1 + 0);
                c1 = *(const float2*)(ear + k1 + 2);
                c2 = *(const float2*)(ear + k1 + 4);
                c3 = *(const float2*)(ear + k1 + 6);
            } else if (q == 2) {
                c0 = *(const float2*)(ear + 48);
            }
            bf1.u[0] = f2b(c0.x) | (f2b(c0.y) << 16);
            bf1.u[1] = f2b(c1.x) | (f2b(c1.y) << 16);
            bf1.u[2] = f2b(c2.x) | (f2b(c2.y) << 16);
            bf1.u[3] = f2b(c3.x) | (f2b(c3.y) << 16);
        }

        // phase 1: t = ssp(m1 @ ea^T + b1) -- all 16 MFMAs, acc1[8] live (8-deep ILP)
        f32x4 acc1[8];
#pragma unroll
        for (int m = 0; m < 8; ++m) {
            f32x4 z = (f32x4)(0.f);
            s16x8 af0 = *(const s16x8*)(m1p + (m * 16 + l15) * 64 + q * 8);
            acc1[m] = __builtin_amdgcn_mfma_f32_16x16x32_bf16(af0, bf0.v, z, 0, 0, 0);
        }
#pragma unroll
        for (int m = 0; m < 8; ++m) {
            s16x8 af1 = *(const s16x8*)(m1p + (m * 16 + l15) * 64 + q * 8 + 32);
            acc1[m] = __builtin_amdgcn_mfma_f32_16x16x32_bf16(af1, bf1.v, acc1[m], 0, 0, 0);
        }

        // bias + sspf + bf16 pack (independent per m; VALU/trans pipelined)
        uint2 p[8];
#pragma unroll
        for (int m = 0; m < 8; ++m) {
            int n0 = m * 16 + q * 4;
            f32x4 bv = *(const f32x4*)(b1p + n0);
            float t0 = sspf(acc1[m][0] + bv[0]);
            float t1 = sspf(acc1[m][1] + bv[1]);
            float t2 = sspf(acc1[m][2] + bv[2]);
            float t3 = sspf(acc1[m][3] + bv[3]);
            p[m].x = f2b(t0) | (f2b(t1) << 16);
            p[m].y = f2b(t2) | (f2b(t3) << 16);
        }

        // segmented-reduction masks (edges dst-sorted; runs contiguous in l15)
        int dprev = __shfl_up(d, 1, 16);
        int dn1 = __shfl_down(d, 1, 16);
        int dn2 = __shfl_down(d, 2, 16);
        int dn4 = __shfl_down(d, 4, 16);
        int dn8 = __shfl_down(d, 8, 16);
        float f1 = ((dn1 == d) && (l15 + 1 < 16)) ? 1.f : 0.f;
        float f2v = ((dn2 == d) && (l15 + 2 < 16)) ? 1.f : 0.f;
        float f4 = ((dn4 == d) && (l15 + 4 < 16)) ? 1.f : 0.f;
        float f8 = ((dn8 == d) && (l15 + 8 < 16)) ? 1.f : 0.f;
        bool head = (eid >= 0) && (l15 == 0 || d != dprev);

        // prefetch all 8 h-fragments (independent; latency hides under MFMAs)
        const float* hrow = h + (size_t)sidx * HID;
        f32x4 hv[8];
#pragma unroll
        for (int m = 0; m < 8; ++m) hv[m] = *(const f32x4*)(hrow + m * 16 + q * 4);

        // phase 2: all 32 MFMAs, ks-outer, a2[8] live (8 independent chains)
        f32x4 a2[8];
#pragma unroll
        for (int m = 0; m < 8; ++m) a2[m] = (f32x4)(0.f);
#pragma unroll
        for (int ks = 0; ks < 4; ++ks) {
            union { s16x8 v; unsigned int u[4]; } bfr;
            bfr.u[0] = p[2 * ks].x;
            bfr.u[1] = p[2 * ks].y;
            bfr.u[2] = p[2 * ks + 1].x;
            bfr.u[3] = p[2 * ks + 1].y;
            int off = (q * 16 + ks * 64) ^ sw;
#pragma unroll
            for (int m = 0; m < 8; ++m) {
                s16x8 af = *(const s16x8*)(sm2 + rowb0 + m * 4096 + off);
                a2[m] = __builtin_amdgcn_mfma_f32_16x16x32_bf16(af, bfr.v, a2[m], 0, 0, 0);
            }
        }

        // epilogue: msg = h[src] * (u + b2) * cw (all m)
#pragma unroll
        for (int m = 0; m < 8; ++m) {
            int n0 = m * 16 + q * 4;
            f32x4 bv = *(const f32x4*)(b2p + n0);
            a2[m][0] = (a2[m][0] + bv[0]) * cw * hv[m][0];
            a2[m][1] = (a2[m][1] + bv[1]) * cw * hv[m][1];
            a2[m][2] = (a2[m][2] + bv[2]) * cw * hv[m][2];
            a2[m][3] = (a2[m][3] + bv[3]) * cw * hv[m][3];
        }

        // segmented suffix-sum via DPP row_shl (pure VALU; 16 independent chains).
        // Pad lanes carry exact 0 (cw=0) so fmaf(0, x, acc) can never see Inf/NaN.
#pragma unroll
        for (int m = 0; m < 8; ++m) {
#pragma unroll
            for (int j = 0; j < 4; ++j) {
                float x = a2[m][j];
                x = fmaf(f1, dpp_shl_f<0x101>(x), x);   // += lane+1 if same run
                x = fmaf(f2v, dpp_shl_f<0x102>(x), x);  // += lane+2
                x = fmaf(f4, dpp_shl_f<0x104>(x), x);   // += lane+4
                x = fmaf(f8, dpp_shl_f<0x108>(x), x);   // += lane+8
                a2[m][j] = x;
            }
        }

        if (head) {
            float* ap = agg + (size_t)d * HID + (q << 2);
#pragma unroll
            for (int m = 0; m < 8; ++m) {
                atomicAdd(ap + m * 16 + 0, a2[m][0]);
                atomicAdd(ap + m * 16 + 1, a2[m][1]);
                atomicAdd(ap + m * 16 + 2, a2[m][2]);
                atomicAdd(ap + m * 16 + 3, a2[m][3]);
            }
        }
    }
}

// ---------------- f32 helpers for lin1 / out (unchanged) ----------------
__device__ __forceinline__ void fma_2x8(float (&acc)[2][8], float2 a, float4 b0, float4 b1) {
    acc[0][0] += a.x * b0.x; acc[0][1] += a.x * b0.y;
    acc[0][2] += a.x * b0.z; acc[0][3] += a.x * b0.w;
    acc[0][4] += a.x * b1.x; acc[0][5] += a.x * b1.y;
    acc[0][6] += a.x * b1.z; acc[0][7] += a.x * b1.w;
    acc[1][0] += a.y * b0.x; acc[1][1] += a.y * b0.y;
    acc[1][2] += a.y * b0.z; acc[1][3] += a.y * b0.w;
    acc[1][4] += a.y * b1.x; acc[1][5] += a.y * b1.y;
    acc[1][6] += a.y * b1.z; acc[1][7] += a.y * b1.w;
}

__device__ __forceinline__ void load_wT32(const float4* __restrict__ w4, int kc,
                                          float (*wT)[132], int tid) {
#pragma unroll
    for (int i = 0; i < 4; ++i) {
        int lin = tid + 256 * i;
        int col = lin >> 3;
        int m = lin & 7;
        float4 v = w4[col * 32 + (kc >> 2) + m];
        wT[4 * m + 0][col] = v.x;
        wT[4 * m + 1][col] = v.y;
        wT[4 * m + 2][col] = v.z;
        wT[4 * m + 3][col] = v.w;
    }
}

__global__ __launch_bounds__(256) void lin1_kernel(const float* __restrict__ x,
                                                   const float* __restrict__ w,
                                                   float* __restrict__ h) {
    __shared__ float xT[HID][36];
    __shared__ float wT[32][132];
    int tid = threadIdx.x;
    int tx = tid & 15, ty = tid >> 4;
    int r0 = blockIdx.x * 32;
    const float4* x4 = (const float4*)x;
#pragma unroll
    for (int i = 0; i < 4; ++i) {
        int lin = tid + 256 * i;
        int r = lin >> 5, m = lin & 31;
        int rr = r0 + r; if (rr > N_NODES_ - 1) rr = N_NODES_ - 1;
        float4 v = x4[rr * 32 + m];
        xT[4 * m + 0][r] = v.x; xT[4 * m + 1][r] = v.y;
        xT[4 * m + 2][r] = v.z; xT[4 * m + 3][r] = v.w;
    }
    float acc[2][8] = {};
    for (int kc = 0; kc < HID; kc += 32) {
        __syncthreads();
        load_wT32((const float4*)w, kc, wT, tid);
        __syncthreads();
#pragma unroll 8
        for (int k2 = 0; k2 < 32; ++k2) {
            float2 a = *(const float2*)&xT[kc + k2][2 * ty];
            float4 b0 = *(const float4*)&wT[k2][8 * tx];
            float4 b1 = *(const float4*)&wT[k2][8 * tx + 4];
            fma_2x8(acc, a, b0, b1);
        }
    }
    float4* h4 = (float4*)h;
#pragma unroll
    for (int i = 0; i < 2; ++i) {
        int row = r0 + 2 * ty + i;
        if (row < N_NODES_) {
            h4[row * 32 + 2 * tx]     = make_float4(acc[i][0], acc[i][1], acc[i][2], acc[i][3]);
            h4[row * 32 + 2 * tx + 1] = make_float4(acc[i][4], acc[i][5], acc[i][6], acc[i][7]);
        }
    }
}

__global__ __launch_bounds__(256) void out_kernel(
    const float* __restrict__ agg,
    const float* __restrict__ w2, const float* __restrict__ b2,
    const float* __restrict__ w3, const float* __restrict__ b3,
    float* __restrict__ out) {
    __shared__ float sT[HID][36];
    __shared__ float wT[32][132];
    int tid = threadIdx.x;
    int tx = tid & 15, ty = tid >> 4;
    int r0 = blockIdx.x * 32;
    const float4* a4 = (const float4*)agg;
#pragma unroll
    for (int i = 0; i < 4; ++i) {
        int lin = tid + 256 * i;
        int r = lin >> 5, m = lin & 31;
        int rr = r0 + r; if (rr > N_NODES_ - 1) rr = N_NODES_ - 1;
        float4 v = a4[rr * 32 + m];
        sT[4 * m + 0][r] = v.x; sT[4 * m + 1][r] = v.y;
        sT[4 * m + 2][r] = v.z; sT[4 * m + 3][r] = v.w;
    }
    float acc[2][8] = {};
    for (int kc = 0; kc < HID; kc += 32) {
        __syncthreads();
        load_wT32((const float4*)w2, kc, wT, tid);
        __syncthreads();
#pragma unroll 8
        for (int k2 = 0; k2 < 32; ++k2) {
            float2 a = *(const float2*)&sT[kc + k2][2 * ty];
            float4 c0 = *(const float4*)&wT[k2][8 * tx];
            float4 c1 = *(const float4*)&wT[k2][8 * tx + 4];
            fma_2x8(acc, a, c0, c1);
        }
    }
    __syncthreads();
#pragma unroll
    for (int j = 0; j < 8; ++j) {
        int col = 8 * tx + j;
        float bbv = b2[col];
        sT[col][2 * ty]     = sspf(acc[0][j] + bbv);
        sT[col][2 * ty + 1] = sspf(acc[1][j] + bbv);
    }
    float acc2[2][8] = {};
    for (int kc = 0; kc < HID; kc += 32) {
        __syncthreads();
        load_wT32((const float4*)w3, kc, wT, tid);
        __syncthreads();
#pragma unroll 8
        for (int k2 = 0; k2 < 32; ++k2) {
            float2 a = *(const float2*)&sT[kc + k2][2 * ty];
            float4 c0 = *(const float4*)&wT[k2][8 * tx];
            float4 c1 = *(const float4*)&wT[k2][8 * tx + 4];
            fma_2x8(acc2, a, c0, c1);
        }
    }
    float4* out4 = (float4*)out;
#pragma unroll
    for (int i = 0; i < 2; ++i) {
        int row = r0 + 2 * ty + i;
        if (row < N_NODES_) {
            out4[row * 32 + 2 * tx] = make_float4(
                acc2[i][0] + b3[8 * tx + 0], acc2[i][1] + b3[8 * tx + 1],
                acc2[i][2] + b3[8 * tx + 2], acc2[i][3] + b3[8 * tx + 3]);
            out4[row * 32 + 2 * tx + 1] = make_float4(
                acc2[i][4] + b3[8 * tx + 4], acc2[i][5] + b3[8 * tx + 5],
                acc2[i][6] + b3[8 * tx + 6], acc2[i][7] + b3[8 * tx + 7]);
        }
    }
}

extern "C" void kernel_launch(void* const* d_in, const int* in_sizes, int n_in,
                              void* d_out, int out_size, void* d_ws, size_t ws_size,
                              hipStream_t stream) {
    const float* x           = (const float*)d_in[0];
    const int*   edge_index  = (const int*)d_in[1];
    const float* edge_weight = (const float*)d_in[2];
    const float* edge_attr   = (const float*)d_in[3];
    const int*   colors      = (const int*)d_in[4];
    const float* m1w         = (const float*)d_in[5];
    const float* m1b         = (const float*)d_in[6];
    const float* m2w         = (const float*)d_in[7];
    const float* m2b         = (const float*)d_in[8];
    const float* lin1w       = (const float*)d_in[9];
    const float* lin2w       = (const float*)d_in[10];
    const float* lin2b       = (const float*)d_in[11];
    const float* linw        = (const float*)d_in[12];
    const float* linb        = (const float*)d_in[13];
    float* out = (float*)d_out;

    // workspace layout (bytes); total 64.59 MB (<= 67.2 MB proven available)
    char* ws = (char*)d_ws;
    float* h      = (float*)(ws);                         // 25,600,000
    float* agg    = (float*)(ws + 25600000);              // 25,600,000
    int*   erec   = (int*)(ws + 51200000);                // 4*CSEG*12 = 12,386,304
    int*   base   = (int*)(ws + 63586304);                // NKEY*4 = 800,000
    int*   csum   = (int*)(ws + 64386304);                // 1,280
    int*   cbase  = (int*)(ws + 64387584);                // 1,280
    int*   g_cnt  = (int*)(ws + 64388864);                // 64
    unsigned short* m1b16 = (unsigned short*)(ws + 64388928);  // 65,536
    unsigned short* m2b16 = (unsigned short*)(ws + 64454464);  // 131,072

    fill_kernel<<<(NCOL * CSEG + 255) / 256, 256, 0, stream>>>(erec, base, (float4*)agg);
    hist_kernel<<<(N_EDGES_ + 255) / 256, 256, 0, stream>>>(colors, edge_index, base);
    scan1_kernel<<<NCHUNK, 256, 0, stream>>>(base, csum);
    scan2_kernel<<<1, 64, 0, stream>>>(csum, cbase, g_cnt);
    scan3_kernel<<<NCHUNK, 256, 0, stream>>>(base, cbase);
    scatter_kernel<<<(N_EDGES_ + 255) / 256, 256, 0, stream>>>(colors, edge_index, edge_weight,
                                                               base, erec);
    wconv_kernel<<<(NCOL * NF * 64 + NCOL * NF * NF + 255) / 256, 256, 0, stream>>>(m1w, m2w, m1b16, m2b16);
    lin1_kernel<<<(N_NODES_ + 31) / 32, 256, 0, stream>>>(x, lin1w, h);
    passA_kernel<<<NCOL * BLKS_PER_C, 256, 0, stream>>>(edge_attr, m1b16, m2b16, m1b, m2b,
                                                        h, erec, g_cnt, agg);
    out_kernel<<<(N_NODES_ + 31) / 32, 256, 0, stream>>>(agg, lin2w, lin2b, linw, linb, out);
}

// Round 10
// 954.759 us; speedup vs baseline: 1.5851x; 1.5851x over previous
//
#include <hip/hip_runtime.h>
#include <math.h>

#define N_NODES_ 50000
#define N_EDGES_ 1000000
#define HID 128
#define NG 50
#define NF 128
#define NCOL 4
#define CSEG 258048            // 64-aligned per-color capacity (>> 250K + 18 sigma)
#define NKEY (NCOL * N_NODES_) // 200000
#define CHUNK 625              // 50000 = 80 * 625
#define NCHUNK_PER_C 80
#define NCHUNK (NCOL * NCHUNK_PER_C)

typedef short s16x8 __attribute__((ext_vector_type(8)));
typedef float f32x4 __attribute__((ext_vector_type(4)));

__device__ __forceinline__ float sspf(float v) {
    // log(1+e^v) - log2, fast-math; for large v avoid inf
    float r = __logf(1.f + __expf(v)) - 0.69314718055994531f;
    return (v > 15.f) ? (v - 0.69314718055994531f) : r;
}

__device__ __forceinline__ unsigned int f2b(float f) {  // f32 -> bf16 (RNE), in low 16
    unsigned int u = __float_as_uint(f);
    return (u + 0x7fffu + ((u >> 16) & 1u)) >> 16;
}

// DPP row_shl:N within 16-lane rows: out[i] = in[i+N], 0 when i+N crosses the row.
template <int CTRL>
__device__ __forceinline__ float dpp_shl_f(float v) {
    return __int_as_float(__builtin_amdgcn_update_dpp(
        0, __float_as_int(v), CTRL, 0xF, 0xF, false));
}

// ---------------- histogram over (color,dst) keys ----------------
__global__ __launch_bounds__(256) void hist_kernel(const int* __restrict__ colors,
                                                   const int* __restrict__ edge_index,
                                                   int* __restrict__ hist) {
    int e = blockIdx.x * 256 + threadIdx.x;
    if (e < N_EDGES_) {
        int key = colors[e] * N_NODES_ + edge_index[N_EDGES_ + e];
        atomicAdd(&hist[key], 1);
    }
}

// ---------------- per-chunk exclusive scan (in place) ----------------
__global__ __launch_bounds__(256) void scan1_kernel(int* __restrict__ hist,
                                                    int* __restrict__ csum) {
    __shared__ int s[CHUNK];
    int b = blockIdx.x;                  // 0..319
    int c = b / NCHUNK_PER_C, ch = b % NCHUNK_PER_C;
    int gofs = c * N_NODES_ + ch * CHUNK;
    for (int i = threadIdx.x; i < CHUNK; i += 256) s[i] = hist[gofs + i];
    __syncthreads();
    if (threadIdx.x == 0) {
        int run = 0;
        for (int i = 0; i < CHUNK; ++i) { int t = s[i]; s[i] = run; run += t; }
        csum[b] = run;
    }
    __syncthreads();
    for (int i = threadIdx.x; i < CHUNK; i += 256) hist[gofs + i] = s[i];
}

__global__ __launch_bounds__(64) void scan2_kernel(const int* __restrict__ csum,
                                                   int* __restrict__ cbase,
                                                   int* __restrict__ g_cnt) {
    int c = threadIdx.x;
    if (c < NCOL) {
        int run = 0;
        for (int j = 0; j < NCHUNK_PER_C; ++j) {
            cbase[c * NCHUNK_PER_C + j] = run;
            run += csum[c * NCHUNK_PER_C + j];
        }
        g_cnt[c] = run;
    }
}

__global__ __launch_bounds__(256) void scan3_kernel(int* __restrict__ hist,
                                                    const int* __restrict__ cbase) {
    int b = blockIdx.x;
    int c = b / NCHUNK_PER_C, ch = b % NCHUNK_PER_C;
    int gofs = c * N_NODES_ + ch * CHUNK;
    int add = cbase[b];
    for (int i = threadIdx.x; i < CHUNK; i += 256) hist[gofs + i] += add;
}

// ---------------- fill pad records + zero hist + zero agg (fused) ----------------
// record = 3 ints: {eid, (d<<16)|src, cw_bits}. Pad: eid=-1, d=0xFFFF (matches only
// other pads; 65535 > any real d<50000), src=0, cw=0 (exact zero so the fma-masked
// DPP scan can never touch Inf/NaN from pad lanes).
__global__ __launch_bounds__(256) void fill_kernel(int* __restrict__ erec,
                                                   int* __restrict__ base,
                                                   float4* __restrict__ agg4) {
    int i = blockIdx.x * 256 + threadIdx.x;
    int nthr = gridDim.x * 256;
    if (i < NCOL * CSEG) {
        erec[3 * i + 0] = -1;
        erec[3 * i + 1] = (int)0xFFFF0000u;
        erec[3 * i + 2] = 0;
    }
    if (i < NKEY) base[i] = 0;
    for (int j = i; j < N_NODES_ * HID / 4; j += nthr)
        agg4[j] = make_float4(0.f, 0.f, 0.f, 0.f);
}

// ---------------- scatter into (color,dst)-sorted order ----------------
// AoS 12B records: one dirty cache line per edge instead of 3 scattered stores.
__global__ __launch_bounds__(256) void scatter_kernel(const int* __restrict__ colors,
                                                      const int* __restrict__ edge_index,
                                                      const float* __restrict__ edge_weight,
                                                      int* __restrict__ base,  // scanned hist (cursor)
                                                      int* __restrict__ erec) {
    int e = blockIdx.x * 256 + threadIdx.x;
    if (e < N_EDGES_) {
        int c = colors[e];
        int d = edge_index[N_EDGES_ + e];
        int s = edge_index[e];
        int key = c * N_NODES_ + d;
        int r = atomicAdd(&base[key], 1);
        float cwv = 0.5f * (__cosf(edge_weight[e] * 0.31415926535897932f) + 1.f);
        size_t slot = (size_t)(c * CSEG + r) * 3;
        erec[slot + 0] = e;
        erec[slot + 1] = (int)(((unsigned)d << 16) | (unsigned)s);
        erec[slot + 2] = (int)__float_as_uint(cwv);
    }
}

// ---------------- convert MLP weights to bf16 ----------------
// m1: zero-padded K (50->64). m2: k-columns permuted by tau so that phase-2's
// B-fragment is a pure register renaming of phase-1's packed MFMA output.
__global__ __launch_bounds__(256) void wconv_kernel(const float* __restrict__ m1w,
                                                    const float* __restrict__ m2w,
                                                    unsigned short* __restrict__ m1b16,
                                                    unsigned short* __restrict__ m2b16) {
    int idx = blockIdx.x * 256 + threadIdx.x;
    if (idx < NCOL * NF * 64) {
        int c = idx / (NF * 64);
        int rem = idx % (NF * 64);
        int n = rem / 64, k = rem % 64;
        float v = (k < NG) ? m1w[(c * NF + n) * NG + k] : 0.f;
        m1b16[idx] = (unsigned short)f2b(v);
    } else if (idx < NCOL * NF * 64 + NCOL * NF * NF) {
        int j = idx - NCOL * NF * 64;
        int cn = j / NF;            // c*NF + n
        int k = j % NF;
        int ks = k >> 5, qk = (k >> 3) & 3, jj = k & 7;
        int tau = ((2 * ks + (jj >> 2)) << 4) | (qk << 2) | (jj & 3);
        m2b16[j] = (unsigned short)f2b(m2w[cn * NF + tau]);
    }
}

// ---------------- fused edge pass ----------------
// Round-9 (resubmit after infra failure): r8 proved the emit path is dominated by
// L2 locality of agg atomic RMWs (same ops, strided schedule -> FETCH 389MB->2.29GB,
// dur 456->1030). Revert to one-tile-per-block (r6) and make the schedule BETTER
// than default: XCD-pinned mapping. Hardware assigns workgroup i to XCD i%8
// (round-robin), so with xcd=bid&7, tile=xcd*512+((bid>>3)&511), each XCD owns a
// contiguous 512-tile dst-range per color: a given agg line is only RMW'd from one
// XCD (no cross-XCD line migration) and the instantaneous window per XCD is ~8x
// narrower than r6. Colors remain dispatch-sequential. 5 blocks/CU (160KB LDS).
__global__ __launch_bounds__(256, 5) void passA_kernel(
    const float* __restrict__ edge_attr,
    const unsigned short* __restrict__ m1b16, const unsigned short* __restrict__ m2b16,
    const float* __restrict__ m1bias, const float* __restrict__ m2bias,
    const float* __restrict__ h, const int* __restrict__ erec,
    const int* __restrict__ g_cnt, float* __restrict__ agg) {

    __shared__ __align__(16) char sm2[32768];   // m2 (one color), XOR-swizzled rows

    int bid = blockIdx.x;
    int xcd = bid & 7;                   // HW round-robin XCD assignment
    int k = bid >> 3;
    int c = k >> 9;                      // colors dispatch-sequential
    int tile = xcd * 512 + (k & 511);    // each XCD owns a contiguous 512-tile range
    int cnt = g_cnt[c];
    if (tile * 64 >= cnt) return;        // uniform early-exit (before barrier)
    int pos0 = c * CSEG + tile * 64;

    int tid = threadIdx.x;
    int wv = tid >> 6;
    int l15 = tid & 15;
    int q = (tid >> 4) & 3;
    int e = (wv << 4) | l15;             // this thread's edge row in tile (MFMA col = l15)

    // ---- stage m2 into LDS, swizzled: byte row*256 + (k0*16 ^ (row&7)<<4)
    {
        const uint4* g4 = (const uint4*)(m2b16 + (size_t)c * NF * NF);
#pragma unroll
        for (int i = 0; i < 8; ++i) {
            int c0 = tid + 256 * i;      // 0..2047 dwordx4 chunks
            int row = c0 >> 4;
            int k0 = c0 & 15;
            int dstb = row * 256 + ((k0 * 16) ^ ((row & 7) << 4));
            *(uint4*)(sm2 + dstb) = g4[c0];
        }
    }

    // per-lane edge record (12B, coalesced; 4x replicated across q groups)
    size_t ri = (size_t)(pos0 + e) * 3;
    int eid = erec[ri + 0];
    unsigned w1 = (unsigned)erec[ri + 1];
    float cw = __int_as_float(erec[ri + 2]);   // exact 0 for pads
    int d = (int)(w1 >> 16);                   // pads: 65535 (only matches pads)
    int sidx = (int)(w1 & 0xFFFFu);

    // phase-1 B-fragments straight from global: lane (q,l15) reads edge_attr row eid,
    // floats [q*8+32ks, q*8+32ks+8), zero-padded for k>=50. 200B rows -> float2 loads.
    union { s16x8 v; unsigned int u[4]; } bf0, bf1;
    {
        const float* ear = edge_attr + (size_t)((eid >= 0) ? eid : 0) * NG;
        float2 a0 = *(const float2*)(ear + q * 8 + 0);
        float2 a1 = *(const float2*)(ear + q * 8 + 2);
        float2 a2v = *(const float2*)(ear + q * 8 + 4);
        float2 a3 = *(const float2*)(ear + q * 8 + 6);
        bf0.u[0] = f2b(a0.x) | (f2b(a0.y) << 16);
        bf0.u[1] = f2b(a1.x) | (f2b(a1.y) << 16);
        bf0.u[2] = f2b(a2v.x) | (f2b(a2v.y) << 16);
        bf0.u[3] = f2b(a3.x) | (f2b(a3.y) << 16);
        float2 c0 = make_float2(0.f, 0.f), c1 = c0, c2 = c0, c3 = c0;
        int k1 = 32 + q * 8;
        if (q < 2) {
            c0 = *(const float2*)(ear + k1 + 0);
            c1 = *(const float2*)(ear + k1 + 2);
            c2 = *(const float2*)(ear + k1 + 4);
            c3 = *(const float2*)(ear + k1 + 6);
        } else if (q == 2) {
            c0 = *(const float2*)(ear + 48);
        }
        bf1.u[0] = f2b(c0.x) | (f2b(c0.y) << 16);
        bf1.u[1] = f2b(c1.x) | (f2b(c1.y) << 16);
        bf1.u[2] = f2b(c2.x) | (f2b(c2.y) << 16);
        bf1.u[3] = f2b(c3.x) | (f2b(c3.y) << 16);
    }

    // phase 1: t = ssp(m1 @ ea^T + b1) -- all 16 MFMAs with acc1[8] live (8-deep ILP)
    f32x4 acc1[8];
    {
        const unsigned short* m1p = m1b16 + (size_t)c * NF * 64;
#pragma unroll
        for (int m = 0; m < 8; ++m) {
            f32x4 z = (f32x4)(0.f);
            s16x8 af0 = *(const s16x8*)(m1p + (m * 16 + l15) * 64 + q * 8);
            acc1[m] = __builtin_amdgcn_mfma_f32_16x16x32_bf16(af0, bf0.v, z, 0, 0, 0);
        }
#pragma unroll
        for (int m = 0; m < 8; ++m) {
            s16x8 af1 = *(const s16x8*)(m1p + (m * 16 + l15) * 64 + q * 8 + 32);
            acc1[m] = __builtin_amdgcn_mfma_f32_16x16x32_bf16(af1, bf1.v, acc1[m], 0, 0, 0);
        }
    }

    // bias + sspf + bf16 pack (independent per m; VALU/trans pipelined)
    uint2 p[8];
    {
        const float* b1p = m1bias + c * NF;
#pragma unroll
        for (int m = 0; m < 8; ++m) {
            int n0 = m * 16 + q * 4;
            f32x4 bv = *(const f32x4*)(b1p + n0);
            float t0 = sspf(acc1[m][0] + bv[0]);
            float t1 = sspf(acc1[m][1] + bv[1]);
            float t2 = sspf(acc1[m][2] + bv[2]);
            float t3 = sspf(acc1[m][3] + bv[3]);
            p[m].x = f2b(t0) | (f2b(t1) << 16);
            p[m].y = f2b(t2) | (f2b(t3) << 16);
        }
    }

    // segmented-reduction masks (edges dst-sorted; runs contiguous in l15)
    int dprev = __shfl_up(d, 1, 16);
    int dn1 = __shfl_down(d, 1, 16);
    int dn2 = __shfl_down(d, 2, 16);
    int dn4 = __shfl_down(d, 4, 16);
    int dn8 = __shfl_down(d, 8, 16);
    float f1 = ((dn1 == d) && (l15 + 1 < 16)) ? 1.f : 0.f;
    float f2v = ((dn2 == d) && (l15 + 2 < 16)) ? 1.f : 0.f;
    float f4 = ((dn4 == d) && (l15 + 4 < 16)) ? 1.f : 0.f;
    float f8 = ((dn8 == d) && (l15 + 8 < 16)) ? 1.f : 0.f;
    bool head = (eid >= 0) && (l15 == 0 || d != dprev);

    __syncthreads();   // m2 staging visible to all waves

    // prefetch all 8 h-fragments (independent loads, latency amortized under MFMAs)
    const float* hrow = h + (size_t)sidx * HID;
    f32x4 hv[8];
#pragma unroll
    for (int m = 0; m < 8; ++m) hv[m] = *(const f32x4*)(hrow + m * 16 + q * 4);

    // phase 2: all 32 MFMAs, ks-outer, a2[8] live (8 independent accumulator chains)
    f32x4 a2[8];
#pragma unroll
    for (int m = 0; m < 8; ++m) a2[m] = (f32x4)(0.f);
    {
        int rowb0 = l15 * 256;
        int sw = (l15 & 7) << 4;
#pragma unroll
        for (int ks = 0; ks < 4; ++ks) {
            union { s16x8 v; unsigned int u[4]; } bfr;
            bfr.u[0] = p[2 * ks].x;
            bfr.u[1] = p[2 * ks].y;
            bfr.u[2] = p[2 * ks + 1].x;
            bfr.u[3] = p[2 * ks + 1].y;
            int off = (q * 16 + ks * 64) ^ sw;
#pragma unroll
            for (int m = 0; m < 8; ++m) {
                s16x8 af = *(const s16x8*)(sm2 + rowb0 + m * 4096 + off);
                a2[m] = __builtin_amdgcn_mfma_f32_16x16x32_bf16(af, bfr.v, a2[m], 0, 0, 0);
            }
        }
    }

    // epilogue: msg = h[src] * (u + b2) * cw (all m)
    {
        const float* b2p = m2bias + c * NF;
#pragma unroll
        for (int m = 0; m < 8; ++m) {
            int n0 = m * 16 + q * 4;
            f32x4 bv = *(const f32x4*)(b2p + n0);
            a2[m][0] = (a2[m][0] + bv[0]) * cw * hv[m][0];
            a2[m][1] = (a2[m][1] + bv[1]) * cw * hv[m][1];
            a2[m][2] = (a2[m][2] + bv[2]) * cw * hv[m][2];
            a2[m][3] = (a2[m][3] + bv[3]) * cw * hv[m][3];
        }
    }

    // segmented suffix-sum via DPP row_shl (pure VALU; 16 independent chains).
    // Pad lanes carry exact 0 (cw=0) so fmaf(0, x, acc) can never see Inf/NaN.
#pragma unroll
    for (int m = 0; m < 8; ++m) {
#pragma unroll
        for (int j = 0; j < 4; ++j) {
            float x = a2[m][j];
            x = fmaf(f1, dpp_shl_f<0x101>(x), x);   // += lane+1 if same run
            x = fmaf(f2v, dpp_shl_f<0x102>(x), x);  // += lane+2
            x = fmaf(f4, dpp_shl_f<0x104>(x), x);   // += lane+4
            x = fmaf(f8, dpp_shl_f<0x108>(x), x);   // += lane+8
            a2[m][j] = x;
        }
    }

    if (head) {
        float* ap = agg + (size_t)d * HID + (q << 2);
#pragma unroll
        for (int m = 0; m < 8; ++m) {
            atomicAdd(ap + m * 16 + 0, a2[m][0]);
            atomicAdd(ap + m * 16 + 1, a2[m][1]);
            atomicAdd(ap + m * 16 + 2, a2[m][2]);
            atomicAdd(ap + m * 16 + 3, a2[m][3]);
        }
    }
}

// ---------------- f32 helpers for lin1 / out (unchanged) ----------------
__device__ __forceinline__ void fma_2x8(float (&acc)[2][8], float2 a, float4 b0, float4 b1) {
    acc[0][0] += a.x * b0.x; acc[0][1] += a.x * b0.y;
    acc[0][2] += a.x * b0.z; acc[0][3] += a.x * b0.w;
    acc[0][4] += a.x * b1.x; acc[0][5] += a.x * b1.y;
    acc[0][6] += a.x * b1.z; acc[0][7] += a.x * b1.w;
    acc[1][0] += a.y * b0.x; acc[1][1] += a.y * b0.y;
    acc[1][2] += a.y * b0.z; acc[1][3] += a.y * b0.w;
    acc[1][4] += a.y * b1.x; acc[1][5] += a.y * b1.y;
    acc[1][6] += a.y * b1.z; acc[1][7] += a.y * b1.w;
}

__device__ __forceinline__ void load_wT32(const float4* __restrict__ w4, int kc,
                                          float (*wT)[132], int tid) {
#pragma unroll
    for (int i = 0; i < 4; ++i) {
        int lin = tid + 256 * i;
        int col = lin >> 3;
        int m = lin & 7;
        float4 v = w4[col * 32 + (kc >> 2) + m];
        wT[4 * m + 0][col] = v.x;
        wT[4 * m + 1][col] = v.y;
        wT[4 * m + 2][col] = v.z;
        wT[4 * m + 3][col] = v.w;
    }
}

__global__ __launch_bounds__(256) void lin1_kernel(const float* __restrict__ x,
                                                   const float* __restrict__ w,
                                                   float* __restrict__ h) {
    __shared__ float xT[HID][36];
    __shared__ float wT[32][132];
    int tid = threadIdx.x;
    int tx = tid & 15, ty = tid >> 4;
    int r0 = blockIdx.x * 32;
    const float4* x4 = (const float4*)x;
#pragma unroll
    for (int i = 0; i < 4; ++i) {
        int lin = tid + 256 * i;
        int r = lin >> 5, m = lin & 31;
        int rr = r0 + r; if (rr > N_NODES_ - 1) rr = N_NODES_ - 1;
        float4 v = x4[rr * 32 + m];
        xT[4 * m + 0][r] = v.x; xT[4 * m + 1][r] = v.y;
        xT[4 * m + 2][r] = v.z; xT[4 * m + 3][r] = v.w;
    }
    float acc[2][8] = {};
    for (int kc = 0; kc < HID; kc += 32) {
        __syncthreads();
        load_wT32((const float4*)w, kc, wT, tid);
        __syncthreads();
#pragma unroll 8
        for (int k2 = 0; k2 < 32; ++k2) {
            float2 a = *(const float2*)&xT[kc + k2][2 * ty];
            float4 b0 = *(const float4*)&wT[k2][8 * tx];
            float4 b1 = *(const float4*)&wT[k2][8 * tx + 4];
            fma_2x8(acc, a, b0, b1);
        }
    }
    float4* h4 = (float4*)h;
#pragma unroll
    for (int i = 0; i < 2; ++i) {
        int row = r0 + 2 * ty + i;
        if (row < N_NODES_) {
            h4[row * 32 + 2 * tx]     = make_float4(acc[i][0], acc[i][1], acc[i][2], acc[i][3]);
            h4[row * 32 + 2 * tx + 1] = make_float4(acc[i][4], acc[i][5], acc[i][6], acc[i][7]);
        }
    }
}

__global__ __launch_bounds__(256) void out_kernel(
    const float* __restrict__ agg,
    const float* __restrict__ w2, const float* __restrict__ b2,
    const float* __restrict__ w3, const float* __restrict__ b3,
    float* __restrict__ out) {
    __shared__ float sT[HID][36];
    __shared__ float wT[32][132];
    int tid = threadIdx.x;
    int tx = tid & 15, ty = tid >> 4;
    int r0 = blockIdx.x * 32;
    const float4* a4 = (const float4*)agg;
#pragma unroll
    for (int i = 0; i < 4; ++i) {
        int lin = tid + 256 * i;
        int r = lin >> 5, m = lin & 31;
        int rr = r0 + r; if (rr > N_NODES_ - 1) rr = N_NODES_ - 1;
        float4 v = a4[rr * 32 + m];
        sT[4 * m + 0][r] = v.x; sT[4 * m + 1][r] = v.y;
        sT[4 * m + 2][r] = v.z; sT[4 * m + 3][r] = v.w;
    }
    float acc[2][8] = {};
    for (int kc = 0; kc < HID; kc += 32) {
        __syncthreads();
        load_wT32((const float4*)w2, kc, wT, tid);
        __syncthreads();
#pragma unroll 8
        for (int k2 = 0; k2 < 32; ++k2) {
            float2 a = *(const float2*)&sT[kc + k2][2 * ty];
            float4 c0 = *(const float4*)&wT[k2][8 * tx];
            float4 c1 = *(const float4*)&wT[k2][8 * tx + 4];
            fma_2x8(acc, a, c0, c1);
        }
    }
    __syncthreads();
#pragma unroll
    for (int j = 0; j < 8; ++j) {
        int col = 8 * tx + j;
        float bbv = b2[col];
        sT[col][2 * ty]     = sspf(acc[0][j] + bbv);
        sT[col][2 * ty + 1] = sspf(acc[1][j] + bbv);
    }
    float acc2[2][8] = {};
    for (int kc = 0; kc < HID; kc += 32) {
        __syncthreads();
        load_wT32((const float4*)w3, kc, wT, tid);
        __syncthreads();
#pragma unroll 8
        for (int k2 = 0; k2 < 32; ++k2) {
            float2 a = *(const float2*)&sT[kc + k2][2 * ty];
            float4 c0 = *(const float4*)&wT[k2][8 * tx];
            float4 c1 = *(const float4*)&wT[k2][8 * tx + 4];
            fma_2x8(acc2, a, c0, c1);
        }
    }
    float4* out4 = (float4*)out;
#pragma unroll
    for (int i = 0; i < 2; ++i) {
        int row = r0 + 2 * ty + i;
        if (row < N_NODES_) {
            out4[row * 32 + 2 * tx] = make_float4(
                acc2[i][0] + b3[8 * tx + 0], acc2[i][1] + b3[8 * tx + 1],
                acc2[i][2] + b3[8 * tx + 2], acc2[i][3] + b3[8 * tx + 3]);
            out4[row * 32 + 2 * tx + 1] = make_float4(
                acc2[i][4] + b3[8 * tx + 4], acc2[i][5] + b3[8 * tx + 5],
                acc2[i][6] + b3[8 * tx + 6], acc2[i][7] + b3[8 * tx + 7]);
        }
    }
}

extern "C" void kernel_launch(void* const* d_in, const int* in_sizes, int n_in,
                              void* d_out, int out_size, void* d_ws, size_t ws_size,
                              hipStream_t stream) {
    const float* x           = (const float*)d_in[0];
    const int*   edge_index  = (const int*)d_in[1];
    const float* edge_weight = (const float*)d_in[2];
    const float* edge_attr   = (const float*)d_in[3];
    const int*   colors      = (const int*)d_in[4];
    const float* m1w         = (const float*)d_in[5];
    const float* m1b         = (const float*)d_in[6];
    const float* m2w         = (const float*)d_in[7];
    const float* m2b         = (const float*)d_in[8];
    const float* lin1w       = (const float*)d_in[9];
    const float* lin2w       = (const float*)d_in[10];
    const float* lin2b       = (const float*)d_in[11];
    const float* linw        = (const float*)d_in[12];
    const float* linb        = (const float*)d_in[13];
    float* out = (float*)d_out;

    // workspace layout (bytes); total 64.59 MB (<= 67.2 MB proven available)
    char* ws = (char*)d_ws;
    float* h      = (float*)(ws);                         // 25,600,000
    float* agg    = (float*)(ws + 25600000);              // 25,600,000
    int*   erec   = (int*)(ws + 51200000);                // 4*CSEG*12 = 12,386,304
    int*   base   = (int*)(ws + 63586304);                // NKEY*4 = 800,000
    int*   csum   = (int*)(ws + 64386304);                // 1,280
    int*   cbase  = (int*)(ws + 64387584);                // 1,280
    int*   g_cnt  = (int*)(ws + 64388864);                // 64
    unsigned short* m1b16 = (unsigned short*)(ws + 64388928);  // 65,536
    unsigned short* m2b16 = (unsigned short*)(ws + 64454464);  // 131,072

    fill_kernel<<<(NCOL * CSEG + 255) / 256, 256, 0, stream>>>(erec, base, (float4*)agg);
    hist_kernel<<<(N_EDGES_ + 255) / 256, 256, 0, stream>>>(colors, edge_index, base);
    scan1_kernel<<<NCHUNK, 256, 0, stream>>>(base, csum);
    scan2_kernel<<<1, 64, 0, stream>>>(csum, cbase, g_cnt);
    scan3_kernel<<<NCHUNK, 256, 0, stream>>>(base, cbase);
    scatter_kernel<<<(N_EDGES_ + 255) / 256, 256, 0, stream>>>(colors, edge_index, edge_weight,
                                                               base, erec);
    wconv_kernel<<<(NCOL * NF * 64 + NCOL * NF * NF + 255) / 256, 256, 0, stream>>>(m1w, m2w, m1b16, m2b16);
    lin1_kernel<<<(N_NODES_ + 31) / 32, 256, 0, stream>>>(x, lin1w, h);
    passA_kernel<<<NCOL * 4096, 256, 0, stream>>>(edge_attr, m1b16, m2b16, m1b, m2b,
                                                  h, erec, g_cnt, agg);
    out_kernel<<<(N_NODES_ + 31) / 32, 256, 0, stream>>>(agg, lin2w, lin2b, linw, linb, out);
}